// Round 2
// baseline (1563.937 us; speedup 1.0000x reference)
//
#include <hip/hip_runtime.h>
#include <hip/hip_bf16.h>

#define B_ 256
#define T_ 512
#define I_ 128
#define H_ 256

// ---------- xw value type helpers (fp32 normally; bf16 fallback if ws small) ----
__device__ inline float xwt_to_float(float v) { return v; }
__device__ inline float xwt_to_float(__hip_bfloat16 v) { return __bfloat162float(v); }
__device__ inline void xwt_store(float* p, float v) { *p = v; }
__device__ inline void xwt_store(__hip_bfloat16* p, float v) { *p = __float2bfloat16(v); }

// =====================================================================
// Kernel 1: xw[m][j] = dot(x[m,0:128], W_ih[j,0:128]) + (b_ih[j]+b_hh[j])
// (unchanged from round 1 — scan dominates; revisit later)
// =====================================================================
template <typename XWT>
__global__ __launch_bounds__(256) void xw_gemm(const float* __restrict__ x,
                                               const float* __restrict__ W_ih,
                                               const float* __restrict__ b_ih,
                                               const float* __restrict__ b_hh,
                                               XWT* __restrict__ xw) {
    __shared__ float xs[128][33];
    __shared__ float wsm[128][33];

    const int bx = blockIdx.x;
    const int mb = bx >> 1;
    const int nb = bx & 1;
    const int m0 = mb * 128;
    const int n0 = nb * 128;
    const int tid = (int)threadIdx.x;
    const int ty = tid >> 4;
    const int tx = tid & 15;

    float acc[8][8];
#pragma unroll
    for (int i = 0; i < 8; ++i)
#pragma unroll
        for (int j = 0; j < 8; ++j) acc[i][j] = 0.f;

    for (int kc = 0; kc < I_; kc += 32) {
        {
            const int r  = tid >> 1;
            const int ks = (tid & 1) * 16;
            const float4* sx = reinterpret_cast<const float4*>(x + (size_t)(m0 + r) * I_ + kc + ks);
            float4 a0 = sx[0], a1 = sx[1], a2 = sx[2], a3 = sx[3];
            const float4* sw = reinterpret_cast<const float4*>(W_ih + (size_t)(n0 + r) * I_ + kc + ks);
            float4 b0 = sw[0], b1 = sw[1], b2 = sw[2], b3 = sw[3];
            float* dx = &xs[r][ks];
            dx[0]=a0.x; dx[1]=a0.y; dx[2]=a0.z; dx[3]=a0.w;
            dx[4]=a1.x; dx[5]=a1.y; dx[6]=a1.z; dx[7]=a1.w;
            dx[8]=a2.x; dx[9]=a2.y; dx[10]=a2.z; dx[11]=a2.w;
            dx[12]=a3.x; dx[13]=a3.y; dx[14]=a3.z; dx[15]=a3.w;
            float* dw = &wsm[r][ks];
            dw[0]=b0.x; dw[1]=b0.y; dw[2]=b0.z; dw[3]=b0.w;
            dw[4]=b1.x; dw[5]=b1.y; dw[6]=b1.z; dw[7]=b1.w;
            dw[8]=b2.x; dw[9]=b2.y; dw[10]=b2.z; dw[11]=b2.w;
            dw[12]=b3.x; dw[13]=b3.y; dw[14]=b3.z; dw[15]=b3.w;
        }
        __syncthreads();
#pragma unroll
        for (int k = 0; k < 32; ++k) {
            float a[8], bv[8];
#pragma unroll
            for (int i = 0; i < 8; ++i) a[i] = xs[ty + 16 * i][k];
#pragma unroll
            for (int j = 0; j < 8; ++j) bv[j] = wsm[tx + 16 * j][k];
#pragma unroll
            for (int i = 0; i < 8; ++i)
#pragma unroll
                for (int j = 0; j < 8; ++j) acc[i][j] = fmaf(a[i], bv[j], acc[i][j]);
        }
        __syncthreads();
    }

    float bias[8];
#pragma unroll
    for (int j = 0; j < 8; ++j) {
        const int n = n0 + tx + 16 * j;
        bias[j] = b_ih[n] + b_hh[n];
    }
#pragma unroll
    for (int i = 0; i < 8; ++i) {
        const size_t row = (size_t)(m0 + ty + 16 * i) * H_;
#pragma unroll
        for (int j = 0; j < 8; ++j) {
            xwt_store(&xw[row + n0 + tx + 16 * j], acc[i][j] + bias[j]);
        }
    }
}

// =====================================================================
// Kernel 2: sequential scan. One WG (256 threads, 4 waves) per batch row.
// Thread j caches W_hh row j in 256 VGPRs. Round 1 showed the compiler
// SINKS these loads back into the t-loop (VGPR_Count=140, L2-BW-bound at
// 256 KB/CU/step). Fix: empty inline-asm with "+v" on every component
// makes the loaded values opaque -> cannot be rematerialized from memory.
// __launch_bounds__(256,1): 1 wave/SIMD -> 512-VGPR budget; grid = 256 =
// #CUs so extra occupancy is useless anyway.
// =====================================================================
template <typename XWT>
__global__ __launch_bounds__(256, 1) void rnn_scan(const XWT* __restrict__ xw,
                                                   const float* __restrict__ W_hh,
                                                   const float* __restrict__ fc_w,
                                                   const float* __restrict__ fc_b,
                                                   float* __restrict__ out) {
    __shared__ __attribute__((aligned(16))) float hbuf[2][H_];
    __shared__ float red[H_];

    const int b = (int)blockIdx.x;
    const int j = (int)threadIdx.x;

    // W_hh row j -> registers (256 floats as 64 float4)
    float4 w4[64];
    const float4* wrow = reinterpret_cast<const float4*>(W_hh + (size_t)j * H_);
#pragma unroll
    for (int q = 0; q < 64; ++q) w4[q] = wrow[q];
    // Force VGPR residency: make each component opaque to the optimizer so
    // the loads above cannot be sunk into the t-loop (round-1 failure mode).
#pragma unroll
    for (int q = 0; q < 64; ++q) {
        asm volatile("" : "+v"(w4[q].x), "+v"(w4[q].y), "+v"(w4[q].z), "+v"(w4[q].w));
    }

    hbuf[0][j] = 0.f;
    __syncthreads();

    const XWT* xwp = xw + (size_t)b * T_ * H_ + j;
    float xw_next = xwt_to_float(xwp[0]);

    int cur = 0;
    for (int t = 0; t < T_; ++t) {
        float acc = xw_next;
        if (t + 1 < T_) xw_next = xwt_to_float(xwp[(size_t)(t + 1) * H_]);  // prefetch (independent of h)

        const float4* h4 = reinterpret_cast<const float4*>(hbuf[cur]);
#pragma unroll
        for (int q = 0; q < 64; ++q) {
            float4 hv = h4[q];
            acc = fmaf(hv.x, w4[q].x, acc);
            acc = fmaf(hv.y, w4[q].y, acc);
            acc = fmaf(hv.z, w4[q].z, acc);
            acc = fmaf(hv.w, w4[q].w, acc);
        }
        const float hn = tanhf(acc);
        hbuf[cur ^ 1][j] = hn;   // write buffer nobody reads this step
        __syncthreads();
        cur ^= 1;
    }

    // fc head: out[b] = dot(h_T, fc_w) + fc_b   (O = 1)
    red[j] = hbuf[cur][j] * fc_w[j];
    __syncthreads();
    for (int s = 128; s > 0; s >>= 1) {
        if (j < s) red[j] += red[j + s];
        __syncthreads();
    }
    if (j == 0) out[b] = red[0] + fc_b[0];
}

// =====================================================================
extern "C" void kernel_launch(void* const* d_in, const int* in_sizes, int n_in,
                              void* d_out, int out_size, void* d_ws, size_t ws_size,
                              hipStream_t stream) {
    const float* x    = (const float*)d_in[0];
    const float* W_ih = (const float*)d_in[1];
    const float* W_hh = (const float*)d_in[2];
    const float* b_ih = (const float*)d_in[3];
    const float* b_hh = (const float*)d_in[4];
    const float* fc_w = (const float*)d_in[5];
    const float* fc_b = (const float*)d_in[6];
    float* out = (float*)d_out;

    const int grid1 = (B_ * T_ / 128) * (H_ / 128);  // 2048

    const size_t need_f32 = (size_t)B_ * T_ * H_ * sizeof(float);  // 134 MB
    if (ws_size >= need_f32) {
        float* xw = (float*)d_ws;
        xw_gemm<float><<<grid1, 256, 0, stream>>>(x, W_ih, b_ih, b_hh, xw);
        rnn_scan<float><<<B_, 256, 0, stream>>>(xw, W_hh, fc_w, fc_b, out);
    } else {
        __hip_bfloat16* xw = (__hip_bfloat16*)d_ws;
        xw_gemm<__hip_bfloat16><<<grid1, 256, 0, stream>>>(x, W_ih, b_ih, b_hh, xw);
        rnn_scan<__hip_bfloat16><<<B_, 256, 0, stream>>>(xw, W_hh, fc_w, fc_b, out);
    }
}

// Round 3
// 788.381 us; speedup vs baseline: 1.9837x; 1.9837x over previous
//
#include <hip/hip_runtime.h>
#include <hip/hip_bf16.h>

#define B_ 256
#define T_ 512
#define I_ 128
#define H_ 256

typedef __bf16 bf16x8 __attribute__((ext_vector_type(8)));
typedef float  f32x4  __attribute__((ext_vector_type(4)));
typedef unsigned short u16;
typedef unsigned int   u32;

union U16x8Cast { uint4 v; bf16x8 b; };

__device__ inline u16 f2b(float f) {           // fp32 -> bf16 bits (RNE)
    union { __bf16 h; u16 u; } c; c.h = (__bf16)f; return c.u;
}
__device__ inline bf16x8 pack8(float4 lo, float4 hi) {
    bf16x8 f;
    f[0]=(__bf16)lo.x; f[1]=(__bf16)lo.y; f[2]=(__bf16)lo.z; f[3]=(__bf16)lo.w;
    f[4]=(__bf16)hi.x; f[5]=(__bf16)hi.y; f[6]=(__bf16)hi.z; f[7]=(__bf16)hi.w;
    return f;
}
__device__ inline float fast_tanh(float x) {
    float e = __expf(2.f * x);                 // inf-safe: x>>0 -> 1, x<<0 -> -1
    return 1.f - 2.f / (e + 1.f);
}
// 4-element xw load -> f32x4 (fp32 or bf16 workspace)
__device__ inline f32x4 xw_load4(const float* p) {
    float4 v = *(const float4*)p;
    f32x4 r; r[0]=v.x; r[1]=v.y; r[2]=v.z; r[3]=v.w; return r;
}
__device__ inline f32x4 xw_load4(const __hip_bfloat16* p) {
    uint2 u = *(const uint2*)p;
    f32x4 r;
    r[0] = __uint_as_float(u.x << 16);
    r[1] = __uint_as_float(u.x & 0xFFFF0000u);
    r[2] = __uint_as_float(u.y << 16);
    r[3] = __uint_as_float(u.y & 0xFFFF0000u);
    return r;
}
__device__ inline void xwt_store(float* p, float v) { *p = v; }
__device__ inline void xwt_store(__hip_bfloat16* p, float v) { *(u16*)p = f2b(v); }

// =====================================================================
// Kernel 1 (MFMA): xw[m][n] = x[m,:]*W_ih[n,:] + b_ih[n] + b_hh[n]
// Grid 4096 x 256 thr. WG: 32 m-rows x 256 n. Wave w: 2 m-tiles x 4 n-tiles
// (n-slice w*64..w*64+63), K=128 in 4 chunks of 32. A = x frags, B = W_ih
// frags, both loaded straight from global (f32) and packed to bf16.
// =====================================================================
template <typename XWT>
__global__ __launch_bounds__(256) void xw_gemm_mfma(const float* __restrict__ x,
                                                    const float* __restrict__ W_ih,
                                                    const float* __restrict__ b_ih,
                                                    const float* __restrict__ b_hh,
                                                    XWT* __restrict__ xw) {
    const int tid  = (int)threadIdx.x;
    const int wave = tid >> 6;
    const int lane = tid & 63;
    const int q    = lane >> 4;
    const int ml   = lane & 15;
    const int m0   = (int)blockIdx.x * 32;
    const int n0   = wave * 64;

    // B-frags: lane holds W_ih[n = n0+tau*16+ml][k = kap*32+q*8 + 0..7]
    bf16x8 wB[4][4];
#pragma unroll
    for (int tau = 0; tau < 4; ++tau) {
        const float* wr = W_ih + (size_t)(n0 + tau * 16 + ml) * I_;
#pragma unroll
        for (int kap = 0; kap < 4; ++kap) {
            const int k0 = kap * 32 + q * 8;
            wB[tau][kap] = pack8(*(const float4*)(wr + k0), *(const float4*)(wr + k0 + 4));
        }
    }
    // A-frags: lane holds x[m = m0+mt*16+ml][k = kap*32+q*8 + 0..7]
    bf16x8 xA[2][4];
#pragma unroll
    for (int mt = 0; mt < 2; ++mt) {
        const float* xr = x + (size_t)(m0 + mt * 16 + ml) * I_;
#pragma unroll
        for (int kap = 0; kap < 4; ++kap) {
            const int k0 = kap * 32 + q * 8;
            xA[mt][kap] = pack8(*(const float4*)(xr + k0), *(const float4*)(xr + k0 + 4));
        }
    }

    f32x4 acc[2][4];
#pragma unroll
    for (int mt = 0; mt < 2; ++mt)
#pragma unroll
        for (int tau = 0; tau < 4; ++tau) acc[mt][tau] = (f32x4)0.f;

#pragma unroll
    for (int kap = 0; kap < 4; ++kap)
#pragma unroll
        for (int mt = 0; mt < 2; ++mt)
#pragma unroll
            for (int tau = 0; tau < 4; ++tau)
                acc[mt][tau] = __builtin_amdgcn_mfma_f32_16x16x32_bf16(
                    xA[mt][kap], wB[tau][kap], acc[mt][tau], 0, 0, 0);

    float bias[4];
#pragma unroll
    for (int tau = 0; tau < 4; ++tau) {
        const int n = n0 + tau * 16 + ml;
        bias[tau] = b_ih[n] + b_hh[n];
    }

    // C layout: lane holds D[m0+mt*16+q*4+r][n0+tau*16+ml]
#pragma unroll
    for (int mt = 0; mt < 2; ++mt)
#pragma unroll
        for (int tau = 0; tau < 4; ++tau) {
            const int n = n0 + tau * 16 + ml;
#pragma unroll
            for (int r = 0; r < 4; ++r) {
                const int mrow = m0 + mt * 16 + q * 4 + r;
                xwt_store(&xw[(size_t)mrow * H_ + n], acc[mt][tau][r] + bias[tau]);
            }
        }
}

// =====================================================================
// Kernel 2 (MFMA scan): h_new^T = tanh(xw_t^T + W_hh * h^T), 16 WGs x 4
// waves, WG owns 16 batch rows. Wave w holds W_hh rows [w*64, w*64+64) as
// A-frags in registers (128 VGPR/lane). h lives in LDS in B-FRAGMENT ORDER:
// byte addr = kap*1024 + lane*16 + j*2 holds h[m=lane&15][k=kap*32+(lane>>4)*8+j]
// -> reads are linear ds_read_b128 (conflict-free); C-layout output maps to
// 4 contiguous bf16 per tile -> ds_write_b64. One barrier/step, ping-pong.
// =====================================================================
template <typename XWT>
__global__ __launch_bounds__(256, 1) void rnn_scan_mfma(const XWT* __restrict__ xw,
                                                        const float* __restrict__ W_hh,
                                                        const float* __restrict__ fc_w,
                                                        const float* __restrict__ fc_b,
                                                        float* __restrict__ out) {
    __shared__ __attribute__((aligned(16))) u16 hbuf[2][4096];  // 2 x 8 KB
    __shared__ float red[4][16];

    const int tid  = (int)threadIdx.x;
    const int wave = tid >> 6;
    const int lane = tid & 63;
    const int q    = lane >> 4;
    const int m    = lane & 15;
    const int b0   = (int)blockIdx.x * 16;

    // W_hh A-frags: lane holds W_hh[n = wave*64+tau*16+m][k = kap*32+q*8 + 0..7]
    bf16x8 wf[4][8];
#pragma unroll
    for (int tau = 0; tau < 4; ++tau) {
        const float* wr = W_hh + (size_t)(wave * 64 + tau * 16 + m) * H_;
#pragma unroll
        for (int kap = 0; kap < 8; ++kap) {
            const int k0 = kap * 32 + q * 8;
            wf[tau][kap] = pack8(*(const float4*)(wr + k0), *(const float4*)(wr + k0 + 4));
        }
    }

    // fc_w frag: lane's C rows are n = wave*64+tau*16+q*4 + (0..3)
    float4 fcw[4];
#pragma unroll
    for (int tau = 0; tau < 4; ++tau)
        fcw[tau] = *(const float4*)(fc_w + wave * 64 + tau * 16 + q * 4);

    // LDS write indices (u16 units) for C->B-frag relayout, per tile
    int widx[4];
#pragma unroll
    for (int tau = 0; tau < 4; ++tau) {
        const int nbw = wave * 64 + tau * 16 + q * 4;
        const int kapw = nbw >> 5;
        const int qd = (nbw >> 3) & 3;
        const int j0 = nbw & 7;                       // 0 or 4
        widx[tau] = kapw * 512 + (qd * 16 + m) * 8 + j0;
    }

    // zero h buffer 0 (h_0 = 0)
    {
        uint4* p = (uint4*)&hbuf[0][0];
        const uint4 z = {0u, 0u, 0u, 0u};
        p[tid] = z; p[tid + 256] = z;
    }
    __syncthreads();

    // xw accumulator-init values: lane reads xw[b0+m][t][wave*64+tau*16+q*4 + 0..3]
    const XWT* xwp = xw + (size_t)(b0 + m) * T_ * H_ + (wave * 64 + q * 4);
    f32x4 xwv[4];
#pragma unroll
    for (int tau = 0; tau < 4; ++tau) xwv[tau] = xw_load4(xwp + tau * 16);

    int cur = 0;
    f32x4 acc[4];
    for (int t = 0; t < T_; ++t) {
#pragma unroll
        for (int tau = 0; tau < 4; ++tau) acc[tau] = xwv[tau];
        if (t + 1 < T_) {                              // prefetch next step's xw
            const XWT* pt = xwp + (size_t)(t + 1) * H_;
#pragma unroll
            for (int tau = 0; tau < 4; ++tau) xwv[tau] = xw_load4(pt + tau * 16);
        }

        const uint4* hb = (const uint4*)&hbuf[cur][0];
#pragma unroll
        for (int kap = 0; kap < 8; ++kap) {
            U16x8Cast c; c.v = hb[kap * 64 + lane];    // linear: conflict-free b128
#pragma unroll
            for (int tau = 0; tau < 4; ++tau)
                acc[tau] = __builtin_amdgcn_mfma_f32_16x16x32_bf16(
                    wf[tau][kap], c.b, acc[tau], 0, 0, 0);
        }

        if (t == T_ - 1) break;                        // last h feeds fc only

        u16* wb = &hbuf[cur ^ 1][0];
#pragma unroll
        for (int tau = 0; tau < 4; ++tau) {
            const float h0 = fast_tanh(acc[tau][0]);
            const float h1 = fast_tanh(acc[tau][1]);
            const float h2 = fast_tanh(acc[tau][2]);
            const float h3 = fast_tanh(acc[tau][3]);
            uint2 pk;
            pk.x = (u32)f2b(h0) | ((u32)f2b(h1) << 16);
            pk.y = (u32)f2b(h2) | ((u32)f2b(h3) << 16);
            *(uint2*)(wb + widx[tau]) = pk;            // 8B aligned
        }
        __syncthreads();
        cur ^= 1;
    }

    // fc head: out[b] = sum_n tanh(acc)[n,b] * fc_w[n] + fc_b
    float partial = 0.f;
#pragma unroll
    for (int tau = 0; tau < 4; ++tau) {
        partial += fast_tanh(acc[tau][0]) * fcw[tau].x;
        partial += fast_tanh(acc[tau][1]) * fcw[tau].y;
        partial += fast_tanh(acc[tau][2]) * fcw[tau].z;
        partial += fast_tanh(acc[tau][3]) * fcw[tau].w;
    }
    partial += __shfl_xor(partial, 16);
    partial += __shfl_xor(partial, 32);
    if (lane < 16) red[wave][m] = partial;
    __syncthreads();
    if (tid < 16)
        out[b0 + tid] = red[0][tid] + red[1][tid] + red[2][tid] + red[3][tid] + fc_b[0];
}

// =====================================================================
extern "C" void kernel_launch(void* const* d_in, const int* in_sizes, int n_in,
                              void* d_out, int out_size, void* d_ws, size_t ws_size,
                              hipStream_t stream) {
    const float* x    = (const float*)d_in[0];
    const float* W_ih = (const float*)d_in[1];
    const float* W_hh = (const float*)d_in[2];
    const float* b_ih = (const float*)d_in[3];
    const float* b_hh = (const float*)d_in[4];
    const float* fc_w = (const float*)d_in[5];
    const float* fc_b = (const float*)d_in[6];
    float* out = (float*)d_out;

    const int grid1 = (B_ * T_) / 32;                  // 4096
    const size_t need_f32 = (size_t)B_ * T_ * H_ * sizeof(float);  // 134 MB

    if (ws_size >= need_f32) {
        float* xwbuf = (float*)d_ws;
        xw_gemm_mfma<float><<<grid1, 256, 0, stream>>>(x, W_ih, b_ih, b_hh, xwbuf);
        rnn_scan_mfma<float><<<B_ / 16, 256, 0, stream>>>(xwbuf, W_hh, fc_w, fc_b, out);
    } else {
        __hip_bfloat16* xwbuf = (__hip_bfloat16*)d_ws;
        xw_gemm_mfma<__hip_bfloat16><<<grid1, 256, 0, stream>>>(x, W_ih, b_ih, b_hh, xwbuf);
        rnn_scan_mfma<__hip_bfloat16><<<B_ / 16, 256, 0, stream>>>(xwbuf, W_hh, fc_w, fc_b, out);
    }
}

// Round 4
// 772.068 us; speedup vs baseline: 2.0256x; 1.0211x over previous
//
#include <hip/hip_runtime.h>
#include <hip/hip_bf16.h>

#define B_ 256
#define T_ 512
#define I_ 128
#define H_ 256

typedef __bf16 bf16x8 __attribute__((ext_vector_type(8)));
typedef float  f32x4  __attribute__((ext_vector_type(4)));
typedef unsigned short u16;
typedef unsigned int   u32;

union U16x8Cast { uint4 v; bf16x8 b; };

__device__ inline u16 f2b(float f) {           // fp32 -> bf16 bits (RNE)
    union { __bf16 h; u16 u; } c; c.h = (__bf16)f; return c.u;
}
__device__ inline bf16x8 pack8(float4 lo, float4 hi) {
    bf16x8 f;
    f[0]=(__bf16)lo.x; f[1]=(__bf16)lo.y; f[2]=(__bf16)lo.z; f[3]=(__bf16)lo.w;
    f[4]=(__bf16)hi.x; f[5]=(__bf16)hi.y; f[6]=(__bf16)hi.z; f[7]=(__bf16)hi.w;
    return f;
}
__device__ inline uint2 pack4(float a, float b, float c, float d) {
    uint2 p;
    p.x = (u32)f2b(a) | ((u32)f2b(b) << 16);
    p.y = (u32)f2b(c) | ((u32)f2b(d) << 16);
    return p;
}
// 4 bf16 (as uint2) -> f32x4
__device__ inline f32x4 b4_to_f32x4(uint2 u) {
    f32x4 r;
    r[0] = __uint_as_float(u.x << 16);
    r[1] = __uint_as_float(u.x & 0xFFFF0000u);
    r[2] = __uint_as_float(u.y << 16);
    r[3] = __uint_as_float(u.y & 0xFFFF0000u);
    return r;
}
// cheap tanh: v_mul+v_exp+v_add+v_rcp+v_fma (round-3 used precise div ~10 instr)
__device__ inline float fast_tanh(float x) {
    float e = __expf(2.f * x);                 // x>>0 -> inf -> r=0 -> 1; x<<0 -> -1
#if __has_builtin(__builtin_amdgcn_rcpf)
    float r = __builtin_amdgcn_rcpf(1.f + e);
#else
    float r = 1.f / (1.f + e);
#endif
    return 1.f - 2.f * r;
}

// =====================================================================
// Kernel 1 (MFMA): xw[t][b][n] = x[bT+t,:]*W_ih[n,:] + b_ih[n] + b_hh[n]
// Operands SWAPPED vs round 3: A = W_ih (M=n), B = x (N=m) so each lane's
// C f32x4 = 4 CONSECUTIVE n at one (t,b) -> uint2 LDS stage, then
// fully-coalesced dwordx4 copy-out to the [t][b][n] bf16 layout.
// WG = 32 m-rows (one b, 32 consecutive t) x 256 n. grid 4096.
// =====================================================================
#define LDST 264   // u16 stride of LDS tile row (264*2=528 B, 16B-aligned rows)
__global__ __launch_bounds__(256) void xw_gemm_mfma(const float* __restrict__ x,
                                                    const float* __restrict__ W_ih,
                                                    const float* __restrict__ b_ih,
                                                    const float* __restrict__ b_hh,
                                                    u16* __restrict__ xw) {
    __shared__ u16 tile[32 * LDST];

    const int tid  = (int)threadIdx.x;
    const int wave = tid >> 6;
    const int lane = tid & 63;
    const int q    = lane >> 4;
    const int ml   = lane & 15;
    const int m0   = (int)blockIdx.x * 32;
    const int b    = m0 >> 9;          // batch row (T_=512 rows per b)
    const int t0   = m0 & 511;
    const int n0   = wave * 64;

    // A-frags: lane holds W_ih[n = n0+tau*16+ml][k = kap*32+q*8 + 0..7]
    bf16x8 wA[4][4];
#pragma unroll
    for (int tau = 0; tau < 4; ++tau) {
        const float* wr = W_ih + (size_t)(n0 + tau * 16 + ml) * I_;
#pragma unroll
        for (int kap = 0; kap < 4; ++kap) {
            const int k0 = kap * 32 + q * 8;
            wA[tau][kap] = pack8(*(const float4*)(wr + k0), *(const float4*)(wr + k0 + 4));
        }
    }
    // B-frags: lane holds x[m = m0+mt*16+ml][k]
    bf16x8 xB[2][4];
#pragma unroll
    for (int mt = 0; mt < 2; ++mt) {
        const float* xr = x + (size_t)(m0 + mt * 16 + ml) * I_;
#pragma unroll
        for (int kap = 0; kap < 4; ++kap) {
            const int k0 = kap * 32 + q * 8;
            xB[mt][kap] = pack8(*(const float4*)(xr + k0), *(const float4*)(xr + k0 + 4));
        }
    }

    f32x4 acc[2][4];
#pragma unroll
    for (int mt = 0; mt < 2; ++mt)
#pragma unroll
        for (int tau = 0; tau < 4; ++tau) acc[mt][tau] = (f32x4)0.f;

#pragma unroll
    for (int kap = 0; kap < 4; ++kap)
#pragma unroll
        for (int mt = 0; mt < 2; ++mt)
#pragma unroll
            for (int tau = 0; tau < 4; ++tau)
                acc[mt][tau] = __builtin_amdgcn_mfma_f32_16x16x32_bf16(
                    wA[tau][kap], xB[mt][kap], acc[mt][tau], 0, 0, 0);

    // bias for lane's 4 consecutive n rows: n = n0+tau*16+q*4 + r
    float4 bias4[4];
#pragma unroll
    for (int tau = 0; tau < 4; ++tau) {
        const int n = n0 + tau * 16 + q * 4;
        float4 bi = *(const float4*)(b_ih + n);
        float4 bh = *(const float4*)(b_hh + n);
        bias4[tau] = make_float4(bi.x + bh.x, bi.y + bh.y, bi.z + bh.z, bi.w + bh.w);
    }

    // C layout: lane = D[n0+tau*16+q*4+r][m-col = mt*16+ml] -> local t-row mt*16+ml
#pragma unroll
    for (int mt = 0; mt < 2; ++mt) {
        const int row = mt * 16 + ml;
#pragma unroll
        for (int tau = 0; tau < 4; ++tau) {
            uint2 pk = pack4(acc[mt][tau][0] + bias4[tau].x,
                             acc[mt][tau][1] + bias4[tau].y,
                             acc[mt][tau][2] + bias4[tau].z,
                             acc[mt][tau][3] + bias4[tau].w);
            *(uint2*)(tile + row * LDST + n0 + tau * 16 + q * 4) = pk;
        }
    }
    __syncthreads();

    // coalesced copy-out: row r (local t), 8 threads x 64 B cover 512 B row
    {
        const int r = tid >> 3;
        const int c = tid & 7;
        const uint4* src = (const uint4*)(tile + r * LDST + c * 32);
        u16* dst = xw + ((size_t)(t0 + r) * B_ + b) * H_ + c * 32;
        uint4 v0 = src[0], v1 = src[1], v2 = src[2], v3 = src[3];
        uint4* d4 = (uint4*)dst;
        d4[0] = v0; d4[1] = v1; d4[2] = v2; d4[3] = v3;
    }
}

// =====================================================================
// Kernel 2 (MFMA scan): 16 WGs x 512 threads (8 waves = 2/SIMD for TLP).
// Wave w owns H rows [w*32, w*32+32) as A-frags (16 bf16x8 = 64 VGPR —
// small enough that the allocator keeps them resident, unlike 128+).
// h ping-pongs in LDS in B-fragment order (linear conflict-free b128).
// xw in [t][b][n]: per-step prefetch is one contiguous 8 KB block.
// =====================================================================
__global__ __launch_bounds__(512, 2) void rnn_scan_mfma(const u16* __restrict__ xw,
                                                        const float* __restrict__ W_hh,
                                                        const float* __restrict__ fc_w,
                                                        const float* __restrict__ fc_b,
                                                        float* __restrict__ out) {
    __shared__ __attribute__((aligned(16))) u16 hbuf[2][4096];  // 2 x 8 KB
    __shared__ float red[8][16];

    const int tid  = (int)threadIdx.x;
    const int wave = tid >> 6;          // 0..7
    const int lane = tid & 63;
    const int q    = lane >> 4;
    const int m    = lane & 15;
    const int b0   = (int)blockIdx.x * 16;

    // W_hh A-frags: lane holds W_hh[n = wave*32+tau2*16+m][k = kap*32+q*8+0..7]
    bf16x8 wf[2][8];
#pragma unroll
    for (int tau2 = 0; tau2 < 2; ++tau2) {
        const float* wr = W_hh + (size_t)(wave * 32 + tau2 * 16 + m) * H_;
#pragma unroll
        for (int kap = 0; kap < 8; ++kap) {
            const int k0 = kap * 32 + q * 8;
            wf[tau2][kap] = pack8(*(const float4*)(wr + k0), *(const float4*)(wr + k0 + 4));
        }
    }

    // fc_w for lane's C rows: n = wave*32+tau2*16+q*4 + 0..3
    float4 fcw[2];
#pragma unroll
    for (int tau2 = 0; tau2 < 2; ++tau2)
        fcw[tau2] = *(const float4*)(fc_w + wave * 32 + tau2 * 16 + q * 4);

    // LDS write indices (u16 units) for C -> B-frag relayout
    int widx[2];
#pragma unroll
    for (int tau2 = 0; tau2 < 2; ++tau2) {
        const int nbw = wave * 32 + tau2 * 16 + q * 4;
        const int kapw = nbw >> 5;
        const int qd   = (nbw >> 3) & 3;
        const int j0   = nbw & 7;       // 0 or 4
        widx[tau2] = kapw * 512 + (qd * 16 + m) * 8 + j0;
    }

    // zero h buffer 0 (h_0 = 0): 8 KB = 512 uint4
    {
        uint4* p = (uint4*)&hbuf[0][0];
        const uint4 z = {0u, 0u, 0u, 0u};
        p[tid] = z;
    }
    __syncthreads();

    // xw ([t][b][n]): lane reads 2 x uint2 at ((t*B_ + b0+m)*H_ + wave*32+tau2*16+q*4)
    const u16* xwp = xw + ((size_t)(b0 + m)) * H_ + (wave * 32 + q * 4);
    const size_t tstride = (size_t)B_ * H_;
    f32x4 xwv[2];
    {
        const u16* p0 = xwp;
        xwv[0] = b4_to_f32x4(*(const uint2*)(p0));
        xwv[1] = b4_to_f32x4(*(const uint2*)(p0 + 16));
    }

    int cur = 0;
    f32x4 acc[2];
    for (int t = 0; t < T_; ++t) {
        acc[0] = xwv[0];
        acc[1] = xwv[1];
        if (t + 1 < T_) {                              // prefetch next step's xw
            const u16* pt = xwp + (size_t)(t + 1) * tstride;
            xwv[0] = b4_to_f32x4(*(const uint2*)(pt));
            xwv[1] = b4_to_f32x4(*(const uint2*)(pt + 16));
        }

        const uint4* hb = (const uint4*)&hbuf[cur][0];
#pragma unroll
        for (int kap = 0; kap < 8; ++kap) {
            U16x8Cast c; c.v = hb[kap * 64 + lane];    // linear: conflict-free b128
            acc[0] = __builtin_amdgcn_mfma_f32_16x16x32_bf16(wf[0][kap], c.b, acc[0], 0, 0, 0);
            acc[1] = __builtin_amdgcn_mfma_f32_16x16x32_bf16(wf[1][kap], c.b, acc[1], 0, 0, 0);
        }

        if (t == T_ - 1) break;                        // last h feeds fc only

        u16* wb = &hbuf[cur ^ 1][0];
#pragma unroll
        for (int tau2 = 0; tau2 < 2; ++tau2) {
            uint2 pk = pack4(fast_tanh(acc[tau2][0]), fast_tanh(acc[tau2][1]),
                             fast_tanh(acc[tau2][2]), fast_tanh(acc[tau2][3]));
            *(uint2*)(wb + widx[tau2]) = pk;           // 8B aligned
        }
        __syncthreads();
        cur ^= 1;
    }

    // fc head: out[b] = sum_n tanh(acc)[n,b] * fc_w[n] + fc_b
    float partial = 0.f;
#pragma unroll
    for (int tau2 = 0; tau2 < 2; ++tau2) {
        partial += fast_tanh(acc[tau2][0]) * fcw[tau2].x;
        partial += fast_tanh(acc[tau2][1]) * fcw[tau2].y;
        partial += fast_tanh(acc[tau2][2]) * fcw[tau2].z;
        partial += fast_tanh(acc[tau2][3]) * fcw[tau2].w;
    }
    partial += __shfl_xor(partial, 16);                // fold q
    partial += __shfl_xor(partial, 32);
    if (lane < 16) red[wave][m] = partial;
    __syncthreads();
    if (tid < 16) {
        float s = red[0][tid] + red[1][tid] + red[2][tid] + red[3][tid]
                + red[4][tid] + red[5][tid] + red[6][tid] + red[7][tid];
        out[b0 + tid] = s + fc_b[0];
    }
}

// =====================================================================
extern "C" void kernel_launch(void* const* d_in, const int* in_sizes, int n_in,
                              void* d_out, int out_size, void* d_ws, size_t ws_size,
                              hipStream_t stream) {
    const float* x    = (const float*)d_in[0];
    const float* W_ih = (const float*)d_in[1];
    const float* W_hh = (const float*)d_in[2];
    const float* b_ih = (const float*)d_in[3];
    const float* b_hh = (const float*)d_in[4];
    const float* fc_w = (const float*)d_in[5];
    const float* fc_b = (const float*)d_in[6];
    float* out = (float*)d_out;

    u16* xwbuf = (u16*)d_ws;                           // 64 MiB bf16 [T][B][H]
    xw_gemm_mfma<<<(B_ * T_) / 32, 256, 0, stream>>>(x, W_ih, b_ih, b_hh, xwbuf);
    rnn_scan_mfma<<<B_ / 16, 512, 0, stream>>>(xwbuf, W_hh, fc_w, fc_b, out);
}